// Round 7
// baseline (352.620 us; speedup 1.0000x reference)
//
#include <hip/hip_runtime.h>

#define LQ        22000
#define LEN_IN    22000
#define NB        2

typedef _Float16 half8 __attribute__((ext_vector_type(8)));
typedef _Float16 half4 __attribute__((ext_vector_type(4)));
typedef _Float16 half2 __attribute__((ext_vector_type(2)));
typedef float    floatx4 __attribute__((ext_vector_type(4)));

__device__ __forceinline__ void gload16(const void* g, void* l) {
    __builtin_amdgcn_global_load_lds(
        (const __attribute__((address_space(1))) void*)g,
        (__attribute__((address_space(3))) void*)l, 16, 0, 0);
}

// ---------------------------------------------------------------------------
// One-shot prep: weight transposes (fp32 -> f16, (K,N)->(N,K)) + bias concat.
// ---------------------------------------------------------------------------
__global__ __launch_bounds__(256) void prep_kernel(
    const float* __restrict__ Wv, const float* __restrict__ Woff,
    const float* __restrict__ Wattn, const float* __restrict__ Wo,
    const float* __restrict__ boff, const float* __restrict__ battn,
    _Float16* __restrict__ WvT, _Float16* __restrict__ WofT,
    _Float16* __restrict__ WoT, float* __restrict__ biascat)
{
    const int i = blockIdx.x * 256 + threadIdx.x;
    if (i < 131072) {                       // Wv (256,512) -> WvT (512,256)
        int k = i >> 9, n = i & 511;
        WvT[n * 256 + k] = (_Float16)Wv[i];
    } else if (i < 163840) {                // Woff (256,128) -> WofT rows 0..127
        int j = i - 131072; int k = j >> 7, n = j & 127;
        WofT[n * 256 + k] = (_Float16)Woff[j];
    } else if (i < 180224) {                // Wattn (256,64) -> WofT rows 128..191
        int j = i - 163840; int k = j >> 6, n = j & 63;
        WofT[(128 + n) * 256 + k] = (_Float16)Wattn[j];
    } else if (i < 311296) {                // Wo (512,256) -> WoT (256,512)
        int j = i - 180224; int k = j >> 8, n = j & 255;
        WoT[n * 512 + k] = (_Float16)Wo[j];
    } else if (i < 311488) {                // bias concat (192)
        int j = i - 311296;
        biascat[j] = (j < 128) ? boff[j] : battn[j - 128];
    }
}

// fp32 -> f16 elementwise (n4 = count/4), coalesced, read-once
__global__ void f32_to_f16_kernel(const float* __restrict__ src,
                                  _Float16* __restrict__ dst, int n4)
{
    int i = blockIdx.x * blockDim.x + threadIdx.x;
    const int stride = gridDim.x * blockDim.x;
    for (; i < n4; i += stride) {
        float4 v = reinterpret_cast<const float4*>(src)[i];
        half4 h;
        h[0] = (_Float16)v.x; h[1] = (_Float16)v.y;
        h[2] = (_Float16)v.z; h[3] = (_Float16)v.w;
        reinterpret_cast<half4*>(dst)[i] = h;
    }
}

// ---------------------------------------------------------------------------
// 2-phase double-buffered f16 MFMA GEMM (catalog T3 "minimum 2-phase"):
// C(MxN) = A @ B + bias, B given as BT(NxK) f16. 128xBN tile, BK=64,
// 256 threads = 4 waves. global_load_lds staging, source-side XOR swizzle
// (byte ^= (row&7)<<4) matched on ds_read. Next tile staged into the
// alternate LDS buffer BEFORE computing the current one; one barrier/iter.
// A must be padded to gridDim.x*128 rows (C stores are M-guarded).
// ---------------------------------------------------------------------------
template<int BN, int K, bool OUT_F16>
__global__ __launch_bounds__(256) void gemm_kernel(
    const _Float16* __restrict__ A,    // (Mpad, K)
    const _Float16* __restrict__ BT,   // (N, K)
    const float* __restrict__ bias,    // (N)
    void* __restrict__ C,              // (M, N)
    int M, int N)
{
    constexpr int FM  = (BN == 128) ? 4 : 2;
    constexpr int BCW = BN / 32;            // B 1KB-chunks per wave
    constexpr int NT  = K / 64;

    __shared__ __align__(16) char sA0[128 * 128];
    __shared__ __align__(16) char sB0[BN * 128];
    __shared__ __align__(16) char sA1[128 * 128];
    __shared__ __align__(16) char sB1[BN * 128];

    const int t    = threadIdx.x;
    const int w    = t >> 6;
    const int lane = t & 63;
    const int m0   = blockIdx.x * 128;
    const int n0   = blockIdx.y * BN;
    const int wr   = (BN == 128) ? (w >> 1) * 64 : w * 32;
    const int wc   = (BN == 128) ? (w & 1) * 64 : 0;

    // staging: chunk = 1KB = 8 rows x 128B; lane covers 16B.
    const int srow = lane >> 3;
    const int scol = ((lane & 7) ^ srow) << 4;     // pre-swizzled source col

    floatx4 acc[FM][4] = {};

    auto stage = [&](char* dA, char* dB, int k0) {
        #pragma unroll
        for (int j = 0; j < 4; ++j) {              // A: 16 chunks, 4/wave
            const int c = w * 4 + j;
            gload16((const char*)A + ((size_t)(m0 + c * 8 + srow) * K + k0) * 2 + scol,
                    dA + c * 1024);
        }
        #pragma unroll
        for (int j = 0; j < BCW; ++j) {            // B: BN/8 chunks
            const int c = w * BCW + j;
            gload16((const char*)BT + ((size_t)(n0 + c * 8 + srow) * K + k0) * 2 + scol,
                    dB + c * 1024);
        }
    };

    auto compute = [&](const char* cA, const char* cB) {
        #pragma unroll
        for (int kb = 0; kb < 2; ++kb) {
            const int kc = kb * 64 + ((lane >> 4) << 4);
            half8 a[FM], b[4];
            #pragma unroll
            for (int fm = 0; fm < FM; ++fm) {
                const int row = wr + fm * 16 + (lane & 15);
                a[fm] = *reinterpret_cast<const half8*>(
                    cA + row * 128 + (kc ^ ((row & 7) << 4)));
            }
            #pragma unroll
            for (int fn = 0; fn < 4; ++fn) {
                const int row = wc + fn * 16 + (lane & 15);
                b[fn] = *reinterpret_cast<const half8*>(
                    cB + row * 128 + (kc ^ ((row & 7) << 4)));
            }
            #pragma unroll
            for (int fm = 0; fm < FM; ++fm)
                #pragma unroll
                for (int fn = 0; fn < 4; ++fn)
                    acc[fm][fn] = __builtin_amdgcn_mfma_f32_16x16x32_f16(
                        a[fm], b[fn], acc[fm][fn], 0, 0, 0);
        }
    };

    stage(sA0, sB0, 0);
    __syncthreads();                               // prologue drain
    #pragma unroll
    for (int it = 0; it < NT; ++it) {
        char* cA = (it & 1) ? sA1 : sA0;
        char* cB = (it & 1) ? sB1 : sB0;
        char* nA = (it & 1) ? sA0 : sA1;
        char* nB = (it & 1) ? sB0 : sB1;
        if (it + 1 < NT) stage(nA, nB, (it + 1) * 64);   // prefetch next tile
        compute(cA, cB);
        __syncthreads();        // waves done reading cA/cB; next-tile loads landed
    }

    // store: C frag mapping col=lane&15, row=(lane>>4)*4+reg
    const int crow = (lane >> 4) * 4;
    const int ccol = lane & 15;
    #pragma unroll
    for (int fm = 0; fm < FM; ++fm) {
        #pragma unroll
        for (int fn = 0; fn < 4; ++fn) {
            const int col = n0 + wc + fn * 16 + ccol;
            const float bb = bias[col];
            #pragma unroll
            for (int r2 = 0; r2 < 4; ++r2) {
                const int row = m0 + wr + fm * 16 + crow + r2;
                if (row < M) {
                    const float val = acc[fm][fn][r2] + bb;
                    if (OUT_F16)
                        ((_Float16*)C)[(size_t)row * N + col] = (_Float16)val;
                    else
                        ((float*)C)[(size_t)row * N + col] = val;
                }
            }
        }
    }
}

// ---------------------------------------------------------------------------
// Sampler: block = 256 threads = 4 waves = 4 queries; each wave owns a query.
// Phase 1 (lane = sample 0..63): softmax + bilinear metadata -> LDS.
// Phase 2 (lane = (head, 8 dims)): half8 gathers + packed f16 FMA.
// ---------------------------------------------------------------------------
__global__ __launch_bounds__(256) void sampler_kernel(
    const _Float16* __restrict__ value,   // (LEN_IN, 8, 64) f16, this image
    const _Float16* __restrict__ logits,  // (LQ, 192) f16, this image
    const float*    __restrict__ refp,    // (LQ, 2, 2), this image
    _Float16* __restrict__ sampled)       // (LQ, 512) f16
{
    const int t    = threadIdx.x;
    const int wq   = t >> 6;
    const int lane = t & 63;
    const int q    = blockIdx.x * 4 + wq;

    __shared__ __align__(16) int4  s_idx[4][72];
    __shared__ __align__(16) uint4 s_w[4][72];

    {   // ---- phase 1: metadata (lane = sample) ----
        const int s = lane;
        const int h = s >> 3;
        const int l = (s >> 2) & 1;
        const int p = s & 3;
        const _Float16* lg = logits + (size_t)q * 192;

        float logit[8];
        float m = -1e30f;
        #pragma unroll
        for (int j = 0; j < 8; ++j) {
            logit[j] = (float)lg[128 + h * 8 + j];
            m = fmaxf(m, logit[j]);
        }
        float den = 0.f;
        #pragma unroll
        for (int j = 0; j < 8; ++j) den += __expf(logit[j] - m);
        const float aw = __expf(logit[l * 4 + p] - m) / den;

        const int Hl = l ? 50 : 100;
        const int Wl = l ? 88 : 176;
        const int st = l ? 17600 : 0;
        const float rx = refp[q * 4 + l * 2 + 0];
        const float ry = refp[q * 4 + l * 2 + 1];
        const float ox = (float)lg[h * 16 + l * 8 + p * 2 + 0];
        const float oy = (float)lg[h * 16 + l * 8 + p * 2 + 1];

        // ((r+o)/W)*W - 0.5 == r+o-0.5 (normalizer cancels)
        const float x = rx + ox - 0.5f;
        const float y = ry + oy - 0.5f;
        const float x0f = floorf(x), y0f = floorf(y);
        const float fx = x - x0f, fy = y - y0f;
        const int x0 = (int)x0f, y0 = (int)y0f;

        int4  iv;
        uint4 wv;
        #pragma unroll
        for (int c = 0; c < 4; ++c) {
            const int xi = x0 + (c & 1);
            const int yi = y0 + (c >> 1);
            const bool valid = (xi >= 0) & (xi < Wl) & (yi >= 0) & (yi < Hl);
            const float wb = ((c & 1) ? fx : 1.f - fx) * ((c >> 1) ? fy : 1.f - fy);
            const float wz = valid ? wb * aw : 0.f;
            const int xc = min(max(xi, 0), Wl - 1);
            const int yc = min(max(yi, 0), Hl - 1);
            iv[c] = st + yc * Wl + xc;
            union { half2 h2; unsigned int u; } cv;
            cv.h2[0] = (_Float16)wz; cv.h2[1] = cv.h2[0];
            wv[c] = cv.u;
        }
        const int slot = h * 9 + (l * 4 + p);
        s_idx[wq][slot] = iv;
        s_w[wq][slot]   = wv;
    }
    __syncthreads();

    // ---- phase 2: gather + packed FMA (lane = head h, dim group d8) ----
    const int h  = lane >> 3;
    const int d8 = (lane & 7) * 8;
    const _Float16* vbase = value + h * 64 + d8;

    half2 acc0 = {0.f16, 0.f16}, acc1 = acc0, acc2 = acc0, acc3 = acc0;
    #pragma unroll
    for (int s8 = 0; s8 < 8; ++s8) {
        const int4  iv = s_idx[wq][h * 9 + s8];
        const uint4 wv = s_w[wq][h * 9 + s8];
        #pragma unroll
        for (int c = 0; c < 4; ++c) {
            const half8 v = *reinterpret_cast<const half8*>(vbase + (size_t)iv[c] * 512);
            union { unsigned int u; half2 h2; } cv; cv.u = wv[c];
            const half2 wh = cv.h2;
            half2 p0; p0[0] = v[0]; p0[1] = v[1];
            half2 p1; p1[0] = v[2]; p1[1] = v[3];
            half2 p2; p2[0] = v[4]; p2[1] = v[5];
            half2 p3; p3[0] = v[6]; p3[1] = v[7];
            acc0 += p0 * wh;
            acc1 += p1 * wh;
            acc2 += p2 * wh;
            acc3 += p3 * wh;
        }
    }
    half8 o;
    o[0] = acc0[0]; o[1] = acc0[1];
    o[2] = acc1[0]; o[3] = acc1[1];
    o[4] = acc2[0]; o[5] = acc2[1];
    o[6] = acc3[0]; o[7] = acc3[1];
    *reinterpret_cast<half8*>(sampled + (size_t)q * 512 + h * 64 + d8) = o;
}

// ---------------------------------------------------------------------------
extern "C" void kernel_launch(void* const* d_in, const int* in_sizes, int n_in,
                              void* d_out, int out_size, void* d_ws, size_t ws_size,
                              hipStream_t stream)
{
    const float* query  = (const float*)d_in[0];
    const float* refp   = (const float*)d_in[1];
    const float* inflat = (const float*)d_in[2];
    const float* Wv     = (const float*)d_in[3];
    const float* bv     = (const float*)d_in[4];
    const float* Woff   = (const float*)d_in[5];
    const float* boff   = (const float*)d_in[6];
    const float* Wattn  = (const float*)d_in[7];
    const float* battn  = (const float*)d_in[8];
    const float* Wo     = (const float*)d_in[9];
    const float* bo     = (const float*)d_in[10];
    float* out = (float*)d_out;

    const int M2 = NB * LQ;          // 44000
    const int MP = 44032;            // 344*128 padded rows

    char* ws = (char*)d_ws;
    size_t off = 0;
    auto take = [&](size_t bytes) { char* p = ws + off; off = (off + bytes + 255) & ~(size_t)255; return p; };
    _Float16* WvT     = (_Float16*)take(512 * 256 * 2);
    _Float16* WofT    = (_Float16*)take(192 * 256 * 2);
    _Float16* WoT     = (_Float16*)take(256 * 512 * 2);
    float*    biascat = (float*)   take(192 * 4);
    // buf0: A-buffer, 44032x256 f16 == 22016x512 f16 (22.5 MB), multi-purpose
    _Float16* buf0    = (_Float16*)take((size_t)MP * 256 * 2);
    _Float16* value   = (_Float16*)take((size_t)M2 * 512 * 2);   // 45.1 MB
    _Float16* logits  = (_Float16*)take((size_t)M2 * 192 * 2);   // 16.9 MB

    prep_kernel<<<(311488 + 255) / 256, 256, 0, stream>>>(
        Wv, Woff, Wattn, Wo, boff, battn, WvT, WofT, WoT, biascat);

    // logits = query @ [Woff|Wattn] + biascat   (both images, M=44000)
    f32_to_f16_kernel<<<2048, 256, 0, stream>>>(query, buf0, M2 * 256 / 4);
    gemm_kernel<64, 256, true><<<dim3(344, 3), 256, 0, stream>>>(
        buf0, WofT, biascat, logits, M2, 192);

    // value = inflat @ Wv + bv                  (both images, M=44000)
    f32_to_f16_kernel<<<2048, 256, 0, stream>>>(inflat, buf0, M2 * 256 / 4);
    gemm_kernel<128, 256, true><<<dim3(344, 4), 256, 0, stream>>>(
        buf0, WvT, bv, value, M2, 512);

    for (int n = 0; n < NB; ++n) {
        // sampled (22000x512 f16) reuses buf0 (A of the out-GEMM, 22016 rows)
        sampler_kernel<<<LQ / 4, 256, 0, stream>>>(
            value  + (size_t)n * LEN_IN * 512,
            logits + (size_t)n * LQ * 192,
            refp   + (size_t)n * LQ * 4,
            buf0);
        gemm_kernel<64, 512, false><<<dim3(172, 4), 256, 0, stream>>>(
            buf0, WoT, bo, out + (size_t)n * LQ * 256, LQ, 256);
    }
}

// Round 9
// 338.177 us; speedup vs baseline: 1.0427x; 1.0427x over previous
//
#include <hip/hip_runtime.h>

#define LQ        22000
#define LEN_IN    22000
#define NB        2

typedef _Float16 half8 __attribute__((ext_vector_type(8)));
typedef _Float16 half4 __attribute__((ext_vector_type(4)));
typedef _Float16 half2 __attribute__((ext_vector_type(2)));
typedef float    floatx4 __attribute__((ext_vector_type(4)));

__device__ __forceinline__ void gload16(const void* g, void* l) {
    __builtin_amdgcn_global_load_lds(
        (const __attribute__((address_space(1))) void*)g,
        (__attribute__((address_space(3))) void*)l, 16, 0, 0);
}

// ---------------------------------------------------------------------------
// One-shot prep: weight transposes (fp32 -> f16, (K,N)->(N,K)) + bias concat.
// ---------------------------------------------------------------------------
__global__ __launch_bounds__(256) void prep_kernel(
    const float* __restrict__ Wv, const float* __restrict__ Woff,
    const float* __restrict__ Wattn, const float* __restrict__ Wo,
    const float* __restrict__ boff, const float* __restrict__ battn,
    _Float16* __restrict__ WvT, _Float16* __restrict__ WofT,
    _Float16* __restrict__ WoT, float* __restrict__ biascat)
{
    const int i = blockIdx.x * 256 + threadIdx.x;
    if (i < 131072) {                       // Wv (256,512) -> WvT (512,256)
        int k = i >> 9, n = i & 511;
        WvT[n * 256 + k] = (_Float16)Wv[i];
    } else if (i < 163840) {                // Woff (256,128) -> WofT rows 0..127
        int j = i - 131072; int k = j >> 7, n = j & 127;
        WofT[n * 256 + k] = (_Float16)Woff[j];
    } else if (i < 180224) {                // Wattn (256,64) -> WofT rows 128..191
        int j = i - 163840; int k = j >> 6, n = j & 63;
        WofT[(128 + n) * 256 + k] = (_Float16)Wattn[j];
    } else if (i < 311296) {                // Wo (512,256) -> WoT (256,512)
        int j = i - 180224; int k = j >> 8, n = j & 255;
        WoT[n * 512 + k] = (_Float16)Wo[j];
    } else if (i < 311488) {                // bias concat (192)
        int j = i - 311296;
        biascat[j] = (j < 128) ? boff[j] : battn[j - 128];
    }
}

// fp32 -> f16 for BOTH query and inflat in one dispatch (n4 = elems/4 each)
__global__ void cvt2_kernel(const float* __restrict__ qsrc,
                            const float* __restrict__ xsrc,
                            _Float16* __restrict__ qdst,
                            _Float16* __restrict__ xdst, int n4)
{
    int i = blockIdx.x * blockDim.x + threadIdx.x;
    const int stride = gridDim.x * blockDim.x;
    for (; i < 2 * n4; i += stride) {
        const bool second = (i >= n4);
        const int j = second ? i - n4 : i;
        const float4 v = reinterpret_cast<const float4*>(second ? xsrc : qsrc)[j];
        half4 h;
        h[0] = (_Float16)v.x; h[1] = (_Float16)v.y;
        h[2] = (_Float16)v.z; h[3] = (_Float16)v.w;
        reinterpret_cast<half4*>(second ? xdst : qdst)[j] = h;
    }
}

// ---------------------------------------------------------------------------
// f16 MFMA GEMM (m97 structure, single LDS buffer, XCD-chunked swizzle):
// C(MxN) = A @ B + bias, B given as BT(NxK) f16. 128xBN tile, BK=64,
// 256 threads = 4 waves. global_load_lds staging, source-side XOR swizzle
// (byte ^= (row&7)<<4) matched on ds_read. 1-D grid = NBX*NBY, N-minor
// flat order + chunked XCD remap so sibling N-blocks (sharing an A tile)
// land on the same XCD's L2. Grid size must be divisible by 8.
// A must be padded to NBX*128 rows (C stores are M-guarded).
// ---------------------------------------------------------------------------
template<int BN, int K, bool OUT_F16>
__global__ __launch_bounds__(256) void gemm_kernel(
    const _Float16* __restrict__ A,    // (Mpad, K)
    const _Float16* __restrict__ BT,   // (N, K)
    const float* __restrict__ bias,    // (N)
    void* __restrict__ C,              // (M, N)
    int M, int N, int NBY)
{
    constexpr int FM  = (BN == 128) ? 4 : 2;
    constexpr int BCW = BN / 32;            // B 1KB-chunks per wave

    __shared__ __align__(16) char sA[128 * 128];
    __shared__ __align__(16) char sB[BN * 128];

    // XCD-chunked bijective remap (gridDim.x % 8 == 0), then N-minor decode
    const int f  = blockIdx.x;
    const int nn = (f & 7) * (gridDim.x >> 3) + (f >> 3);
    const int m0 = (nn / NBY) * 128;
    const int n0 = (nn % NBY) * BN;

    const int t    = threadIdx.x;
    const int w    = t >> 6;
    const int lane = t & 63;
    const int wr   = (BN == 128) ? (w >> 1) * 64 : w * 32;
    const int wc   = (BN == 128) ? (w & 1) * 64 : 0;

    // staging: chunk = 1KB = 8 rows x 128B; lane covers 16B.
    const int srow = lane >> 3;
    const int scol = ((lane & 7) ^ srow) << 4;     // pre-swizzled source col

    floatx4 acc[FM][4] = {};

    for (int it = 0; it < K / 64; ++it) {
        const int k0 = it * 64;
        #pragma unroll
        for (int j = 0; j < 4; ++j) {              // A: 16 chunks, 4/wave
            const int c = w * 4 + j;
            gload16((const char*)A + ((size_t)(m0 + c * 8 + srow) * K + k0) * 2 + scol,
                    sA + c * 1024);
        }
        #pragma unroll
        for (int j = 0; j < BCW; ++j) {            // B: BN/8 chunks
            const int c = w * BCW + j;
            gload16((const char*)BT + ((size_t)(n0 + c * 8 + srow) * K + k0) * 2 + scol,
                    sB + c * 1024);
        }
        __syncthreads();                            // drains vmcnt -> LDS ready

        #pragma unroll
        for (int kb = 0; kb < 2; ++kb) {
            const int kc = kb * 64 + ((lane >> 4) << 4);
            half8 a[FM], b[4];
            #pragma unroll
            for (int fm = 0; fm < FM; ++fm) {
                const int row = wr + fm * 16 + (lane & 15);
                a[fm] = *reinterpret_cast<const half8*>(
                    sA + row * 128 + (kc ^ ((row & 7) << 4)));
            }
            #pragma unroll
            for (int fn = 0; fn < 4; ++fn) {
                const int row = wc + fn * 16 + (lane & 15);
                b[fn] = *reinterpret_cast<const half8*>(
                    sB + row * 128 + (kc ^ ((row & 7) << 4)));
            }
            #pragma unroll
            for (int fm = 0; fm < FM; ++fm)
                #pragma unroll
                for (int fn = 0; fn < 4; ++fn)
                    acc[fm][fn] = __builtin_amdgcn_mfma_f32_16x16x32_f16(
                        a[fm], b[fn], acc[fm][fn], 0, 0, 0);
        }
        __syncthreads();                            // LDS free for next stage
    }

    // store: C frag mapping col=lane&15, row=(lane>>4)*4+reg
    const int crow = (lane >> 4) * 4;
    const int ccol = lane & 15;
    #pragma unroll
    for (int fm = 0; fm < FM; ++fm) {
        #pragma unroll
        for (int fn = 0; fn < 4; ++fn) {
            const int col = n0 + wc + fn * 16 + ccol;
            const float bb = bias[col];
            #pragma unroll
            for (int r2 = 0; r2 < 4; ++r2) {
                const int row = m0 + wr + fm * 16 + crow + r2;
                if (row < M) {
                    const float val = acc[fm][fn][r2] + bb;
                    if (OUT_F16)
                        ((_Float16*)C)[(size_t)row * N + col] = (_Float16)val;
                    else
                        ((float*)C)[(size_t)row * N + col] = val;
                }
            }
        }
    }
}

// ---------------------------------------------------------------------------
// Sampler (both images, one dispatch): block = 4 waves = 4 queries.
// Phase 1 (lane = sample 0..63): softmax + bilinear metadata -> LDS.
// Phase 2 (lane = (head, 8 dims)): half8 gathers + packed f16 FMA.
// ---------------------------------------------------------------------------
__global__ __launch_bounds__(256) void sampler_kernel(
    const _Float16* __restrict__ value,   // (NB, LEN_IN, 8, 64) f16
    const _Float16* __restrict__ logits,  // (NB*LQ, 192) f16
    const float*    __restrict__ refp,    // (NB*LQ, 2, 2)
    _Float16* __restrict__ sampled)       // (NB*LQ, 512) f16
{
    const int t    = threadIdx.x;
    const int wq   = t >> 6;
    const int lane = t & 63;
    const int q    = blockIdx.x * 4 + wq;         // global query (both images)

    __shared__ __align__(16) int4  s_idx[4][72];
    __shared__ __align__(16) uint4 s_w[4][72];

    {   // ---- phase 1: metadata (lane = sample) ----
        const int s = lane;
        const int h = s >> 3;
        const int l = (s >> 2) & 1;
        const int p = s & 3;
        const _Float16* lg = logits + (size_t)q * 192;

        float logit[8];
        float m = -1e30f;
        #pragma unroll
        for (int j = 0; j < 8; ++j) {
            logit[j] = (float)lg[128 + h * 8 + j];
            m = fmaxf(m, logit[j]);
        }
        float den = 0.f;
        #pragma unroll
        for (int j = 0; j < 8; ++j) den += __expf(logit[j] - m);
        const float aw = __expf(logit[l * 4 + p] - m) / den;

        const int Hl = l ? 50 : 100;
        const int Wl = l ? 88 : 176;
        const int st = l ? 17600 : 0;
        const float rx = refp[q * 4 + l * 2 + 0];
        const float ry = refp[q * 4 + l * 2 + 1];
        const float ox = (float)lg[h * 16 + l * 8 + p * 2 + 0];
        const float oy = (float)lg[h * 16 + l * 8 + p * 2 + 1];

        // ((r+o)/W)*W - 0.5 == r+o-0.5 (normalizer cancels)
        const float x = rx + ox - 0.5f;
        const float y = ry + oy - 0.5f;
        const float x0f = floorf(x), y0f = floorf(y);
        const float fx = x - x0f, fy = y - y0f;
        const int x0 = (int)x0f, y0 = (int)y0f;

        int4  iv;
        uint4 wv;
        #pragma unroll
        for (int c = 0; c < 4; ++c) {
            const int xi = x0 + (c & 1);
            const int yi = y0 + (c >> 1);
            const bool valid = (xi >= 0) & (xi < Wl) & (yi >= 0) & (yi < Hl);
            const float wb = ((c & 1) ? fx : 1.f - fx) * ((c >> 1) ? fy : 1.f - fy);
            const float wz = valid ? wb * aw : 0.f;
            const int xc = min(max(xi, 0), Wl - 1);
            const int yc = min(max(yi, 0), Hl - 1);
            iv[c] = st + yc * Wl + xc;
            union { half2 h2; unsigned int u; } cv;
            cv.h2[0] = (_Float16)wz; cv.h2[1] = cv.h2[0];
            wv[c] = cv.u;
        }
        const int slot = h * 9 + (l * 4 + p);
        s_idx[wq][slot] = iv;
        s_w[wq][slot]   = wv;
    }
    __syncthreads();

    // ---- phase 2: gather + packed FMA (lane = head h, dim group d8) ----
    const int h  = lane >> 3;
    const int d8 = (lane & 7) * 8;
    const _Float16* vbase = value + ((size_t)(q / LQ) * LEN_IN) * 512 + h * 64 + d8;

    half2 acc0 = {0.f16, 0.f16}, acc1 = acc0, acc2 = acc0, acc3 = acc0;
    #pragma unroll
    for (int s8 = 0; s8 < 8; ++s8) {
        const int4  iv = s_idx[wq][h * 9 + s8];
        const uint4 wv = s_w[wq][h * 9 + s8];
        #pragma unroll
        for (int c = 0; c < 4; ++c) {
            const half8 v = *reinterpret_cast<const half8*>(vbase + (size_t)iv[c] * 512);
            union { unsigned int u; half2 h2; } cv; cv.u = wv[c];
            const half2 wh = cv.h2;
            half2 p0; p0[0] = v[0]; p0[1] = v[1];
            half2 p1; p1[0] = v[2]; p1[1] = v[3];
            half2 p2; p2[0] = v[4]; p2[1] = v[5];
            half2 p3; p3[0] = v[6]; p3[1] = v[7];
            acc0 += p0 * wh;
            acc1 += p1 * wh;
            acc2 += p2 * wh;
            acc3 += p3 * wh;
        }
    }
    half8 o;
    o[0] = acc0[0]; o[1] = acc0[1];
    o[2] = acc1[0]; o[3] = acc1[1];
    o[4] = acc2[0]; o[5] = acc2[1];
    o[6] = acc3[0]; o[7] = acc3[1];
    *reinterpret_cast<half8*>(sampled + (size_t)q * 512 + h * 64 + d8) = o;
}

// ---------------------------------------------------------------------------
extern "C" void kernel_launch(void* const* d_in, const int* in_sizes, int n_in,
                              void* d_out, int out_size, void* d_ws, size_t ws_size,
                              hipStream_t stream)
{
    const float* query  = (const float*)d_in[0];
    const float* refp   = (const float*)d_in[1];
    const float* inflat = (const float*)d_in[2];
    const float* Wv     = (const float*)d_in[3];
    const float* bv     = (const float*)d_in[4];
    const float* Woff   = (const float*)d_in[5];
    const float* boff   = (const float*)d_in[6];
    const float* Wattn  = (const float*)d_in[7];
    const float* battn  = (const float*)d_in[8];
    const float* Wo     = (const float*)d_in[9];
    const float* bo     = (const float*)d_in[10];
    float* out = (float*)d_out;

    const int M2 = NB * LQ;          // 44000

    char* ws = (char*)d_ws;
    size_t off = 0;
    auto take = [&](size_t bytes) { char* p = ws + off; off = (off + bytes + 255) & ~(size_t)255; return p; };
    _Float16* WvT     = (_Float16*)take(512 * 256 * 2);
    _Float16* WofT    = (_Float16*)take(192 * 256 * 2);
    _Float16* WoT     = (_Float16*)take(256 * 512 * 2);
    float*    biascat = (float*)   take(192 * 4);
    _Float16* qbf     = (_Float16*)take((size_t)44032 * 256 * 2);  // 22.5 MB (padded)
    _Float16* inbf    = (_Float16*)take((size_t)44032 * 256 * 2);  // 22.5 MB (padded)
    _Float16* value   = (_Float16*)take((size_t)M2 * 512 * 2);     // 45.1 MB
    _Float16* logits  = (_Float16*)take((size_t)M2 * 192 * 2);     // 16.9 MB
    // sampled (44032 x 512 f16 = 45.09 MB) aliases qbf+inbf (dead after GEMMs,
    // contiguous, exactly 2 x 22,544,384 B)
    _Float16* sampled = qbf;

    prep_kernel<<<(311488 + 255) / 256, 256, 0, stream>>>(
        Wv, Woff, Wattn, Wo, boff, battn, WvT, WofT, WoT, biascat);

    cvt2_kernel<<<2048, 256, 0, stream>>>(query, inflat, qbf, inbf, M2 * 256 / 4);

    // value = inflat @ Wv + bv       (M=44000, N=512, K=256) grid 344*4=1376
    gemm_kernel<128, 256, true><<<344 * 4, 256, 0, stream>>>(
        inbf, WvT, bv, value, M2, 512, 4);
    // logits = query @ [Woff|Wattn]  (M=44000, N=192, K=256) grid 344*3=1032
    gemm_kernel<64, 256, true><<<344 * 3, 256, 0, stream>>>(
        qbf, WofT, biascat, logits, M2, 192, 3);

    // sampled (both images)
    sampler_kernel<<<M2 / 4, 256, 0, stream>>>(value, logits, refp, sampled);

    // out = sampled @ Wo + bo        (M=44000, N=256, K=512) grid 344*2=688
    gemm_kernel<128, 512, false><<<344 * 2, 256, 0, stream>>>(
        sampled, WoT, bo, out, M2, 256, 2);
}